// Round 10
// baseline (729.908 us; speedup 1.0000x reference)
//
#include <hip/hip_runtime.h>
#include <math.h>

typedef __attribute__((ext_vector_type(8))) unsigned short ushort8_t;
typedef __attribute__((ext_vector_type(8))) short bf16x8;
typedef __attribute__((ext_vector_type(4))) float f32x4;

namespace {

constexpr int Bn = 1024;
constexpr int Rn = 512;
constexpr int An = 196;
constexpr int Gn = 8192;     // P*4R
constexpr int Kcat = 1536;   // 3*R
constexpr int NP = 224;      // padded att cols per set (14 frags)
constexpr long ROWS = (long)Bn * An;  // 200704

__device__ __forceinline__ float b2f(unsigned short u) {
  union { unsigned int i; float f; } v; v.i = ((unsigned int)u) << 16; return v.f;
}
__device__ __forceinline__ unsigned short f2b(float f) {
  union { float f; unsigned int i; } v; v.f = f;
  unsigned int r = v.i + 0x7fffu + ((v.i >> 16) & 1u);
  return (unsigned short)(r >> 16);
}
__device__ __forceinline__ float sigmf(float x) {
  return __builtin_amdgcn_rcpf(1.f + __expf(-x));
}
__device__ __forceinline__ float tanhf_fast(float x) {
  const float e = __expf(2.f * x);
  return 1.f - 2.f * __builtin_amdgcn_rcpf(e + 1.f);
}

// ---- f32 -> bf16 copy, 8 elems/thread
__global__ __launch_bounds__(256)
void f2b_copy(const float* __restrict__ src, unsigned short* __restrict__ dst, long n)
{
  long i = ((long)blockIdx.x * 256 + threadIdx.x) * 8;
  const long stride = (long)gridDim.x * 256 * 8;
  for (; i + 8 <= n; i += stride) {
    float4 a = *(const float4*)(src + i);
    float4 b = *(const float4*)(src + i + 4);
    ushort8_t o;
    o[0] = f2b(a.x); o[1] = f2b(a.y); o[2] = f2b(a.z); o[3] = f2b(a.w);
    o[4] = f2b(b.x); o[5] = f2b(b.y); o[6] = f2b(b.z); o[7] = f2b(b.w);
    *(ushort8_t*)(dst + i) = o;
  }
}

// ---- merged pack kernel (unchanged from round 9)
__global__ __launch_bounds__(256)
void pack_all(const float* __restrict__ Wa0, const float* __restrict__ Wa1,
              const float* __restrict__ Wh0, const float* __restrict__ Wh1,
              const float* __restrict__ inputs, const float* __restrict__ x,
              const float* __restrict__ Wi, const float* __restrict__ Wh,
              const float* __restrict__ Wa,
              unsigned short* __restrict__ Wp, unsigned short* __restrict__ whcat,
              unsigned short* __restrict__ h01,
              unsigned short* __restrict__ X20, unsigned short* __restrict__ X21,
              unsigned short* __restrict__ W2)
{
  const int blk = blockIdx.x;
  if (blk < 112) {
    long i = ((long)blk * 256 + threadIdx.x) * 8;
    if (i >= 2L * NP * 512) return;
    const int set = (int)(i / (NP * 512));
    const int rem = (int)(i % (NP * 512));
    const int row = rem / 512, k = rem % 512;
    ushort8_t o;
    if (row < An) {
      const float* s = (set ? Wa1 : Wa0) + (long)row * 512 + k;
      float4 a = *(const float4*)s, b = *(const float4*)(s + 4);
      o[0] = f2b(a.x); o[1] = f2b(a.y); o[2] = f2b(a.z); o[3] = f2b(a.w);
      o[4] = f2b(b.x); o[5] = f2b(b.y); o[6] = f2b(b.z); o[7] = f2b(b.w);
    } else {
      o = ushort8_t{0,0,0,0,0,0,0,0};
    }
    *(ushort8_t*)(Wp + i) = o;
  } else if (blk < 210) {
    long i = ((long)(blk - 112) * 256 + threadIdx.x) * 8;
    if (i >= 2L * An * 512) return;
    const long half = (long)An * 512;
    const float* s = (i < half) ? Wh0 + i : Wh1 + (i - half);
    float4 v0 = *(const float4*)s, v1 = *(const float4*)(s + 4);
    ushort8_t o;
    o[0] = f2b(v0.x); o[1] = f2b(v0.y); o[2] = f2b(v0.z); o[3] = f2b(v0.w);
    o[4] = f2b(v1.x); o[5] = f2b(v1.y); o[6] = f2b(v1.z); o[7] = f2b(v1.w);
    *(ushort8_t*)(whcat + i) = o;
  } else if (blk < 722) {
    long i = ((long)(blk - 210) * 256 + threadIdx.x) * 8;
    if (i >= 2L * Bn * 512) return;
    const long half = (long)Bn * 512;
    const float* s = (i < half) ? inputs + half + i : inputs + 3 * half + (i - half);
    float4 v0 = *(const float4*)s, v1 = *(const float4*)(s + 4);
    ushort8_t o;
    o[0] = f2b(v0.x); o[1] = f2b(v0.y); o[2] = f2b(v0.z); o[3] = f2b(v0.w);
    o[4] = f2b(v1.x); o[5] = f2b(v1.y); o[6] = f2b(v1.z); o[7] = f2b(v1.w);
    *(ushort8_t*)(h01 + i) = o;
  } else if (blk < 1490) {
    long i = ((long)(blk - 722) * 256 + threadIdx.x) * 8;
    if (i >= 3L * Bn * 512) return;
    const int sec = (int)(i / ((long)Bn * 512));
    const long r = i % ((long)Bn * 512);
    const int b = (int)(r >> 9);
    const int k = (int)(r & 511);
    const float* src = (sec == 0 ? x
                     : sec == 1 ? inputs + (long)Bn * Rn
                     : inputs + 3L * Bn * Rn) + r;
    unsigned short* dst = (sec == 2 ? X21 : X20) + (long)b * Kcat + (sec ? 512 : 0) + k;
    float4 v0 = *(const float4*)src, v1 = *(const float4*)(src + 4);
    ushort8_t o;
    o[0] = f2b(v0.x); o[1] = f2b(v0.y); o[2] = f2b(v0.z); o[3] = f2b(v0.w);
    o[4] = f2b(v1.x); o[5] = f2b(v1.y); o[6] = f2b(v1.z); o[7] = f2b(v1.w);
    *(ushort8_t*)dst = o;
  } else {
    long i = ((long)(blk - 1490) * 256 + threadIdx.x) * 8;
    if (i >= (long)Gn * Kcat) return;
    const int g = (int)(i / Kcat);
    const int k = (int)(i % Kcat);
    const float* src = (k < 512) ? Wi + (long)g * 512 + k
                     : (k < 1024) ? Wh + (long)g * 512 + (k - 512)
                     : Wa + (long)g * 512 + (k - 1024);
    float4 a = *(const float4*)src;
    float4 b = *(const float4*)(src + 4);
    ushort8_t o;
    o[0] = f2b(a.x); o[1] = f2b(a.y); o[2] = f2b(a.z); o[3] = f2b(a.w);
    o[4] = f2b(b.x); o[5] = f2b(b.y); o[6] = f2b(b.z); o[7] = f2b(b.w);
    *(ushort8_t*)(W2 + i) = o;
  }
}

// ---- column-split att-projection, BK=64 + XOR chunk-swizzle (m173 pattern).
// LDS stays LINEAR (gload_lds requirement); the per-lane GLOBAL chunk is
// pre-swizzled c = c' ^ (row&7); ds_read applies the same XOR -> 2 lanes/bank.
// 1-D grid 3136: block d -> row tile x = (d>>4)*8 + (d&7), set = (d>>3)&1.
__global__ __launch_bounds__(512, 4)
void av_cs(const unsigned short* __restrict__ A,
           const unsigned short* __restrict__ Wpad,
           const float* __restrict__ b0vec, const float* __restrict__ b1vec,
           const float* __restrict__ Wd,
           const float* __restrict__ ah0, const float* __restrict__ ah1,
           float* __restrict__ s0, float* __restrict__ s1,
           unsigned short* __restrict__ av_out)
{
  __shared__ unsigned short As[128 * 64];   // 16 KB
  __shared__ unsigned short Bs[224 * 64];   // 28 KB
  __shared__ float wds[NP], bas[NP];
  __shared__ float ahAs[128], ahBs[128];
  __shared__ float sbA[128], sbB[128];

  const int tid = threadIdx.x;
  const int lane = tid & 63, w = tid >> 6;
  const int wr = w >> 1, wc = w & 1;
  const int fr = lane & 15, q = lane >> 4;
  const int d = blockIdx.x;
  const int xt = ((d >> 4) << 3) | (d & 7);
  const int set = (d >> 3) & 1;
  const long row0 = (long)xt * 128;

  if (set == 0) {
    if (tid < NP) {
      wds[tid] = (tid < An) ? Wd[tid] : 0.f;
      bas[tid] = (tid < An) ? b0vec[tid] : 0.f;
    }
    if (tid >= 256 && tid < 384) ahAs[tid - 256] = ah0[row0 + tid - 256];
    if (tid >= 384)              ahBs[tid - 384] = ah1[row0 + tid - 384];
  } else {
    if (tid < NP) bas[tid] = (tid < An) ? b1vec[tid] : 0.f;
  }

  const unsigned short* Ab = A + row0 * 512;
  const unsigned short* Bb = Wpad + (long)set * NP * 512;

  f32x4 acc[2][7] = {};

  const int lr = lane >> 3;                 // row within 8-row group
  const int lc = (lane & 7) ^ lr;           // swizzled global chunk (16B units)

  for (int kt = 0; kt < 512; kt += 64) {
    // A: wave w stages rows [w*16, w*16+16)
#pragma unroll
    for (int i = 0; i < 2; ++i) {
      const int r = w * 16 + i * 8 + lr;
      const unsigned short* src = Ab + (long)r * 512 + kt + lc * 8;
      __builtin_amdgcn_global_load_lds(
          (const __attribute__((address_space(1))) unsigned int*)src,
          (__attribute__((address_space(3))) unsigned int*)(As + (w * 16 + i * 8) * 64),
          16, 0, 0);
    }
    // B: groups g = w, w+8, w+16 (+ w+24 for w<4); group g = rows [g*8, g*8+8)
#pragma unroll
    for (int i = 0; i < 3; ++i) {
      const int g = w + i * 8;
      const int r = g * 8 + lr;
      const unsigned short* src = Bb + (long)r * 512 + kt + lc * 8;
      __builtin_amdgcn_global_load_lds(
          (const __attribute__((address_space(1))) unsigned int*)src,
          (__attribute__((address_space(3))) unsigned int*)(Bs + g * 8 * 64),
          16, 0, 0);
    }
    if (w < 4) {
      const int g = w + 24;
      const int r = g * 8 + lr;
      const unsigned short* src = Bb + (long)r * 512 + kt + lc * 8;
      __builtin_amdgcn_global_load_lds(
          (const __attribute__((address_space(1))) unsigned int*)src,
          (__attribute__((address_space(3))) unsigned int*)(Bs + g * 8 * 64),
          16, 0, 0);
    }
    __syncthreads();
#pragma unroll
    for (int s = 0; s < 2; ++s) {
      bf16x8 af[2], bfr[7];
#pragma unroll
      for (int m = 0; m < 2; ++m) {
        const int ar = wr * 32 + m * 16 + fr;
        const int cp = (s * 4 + q) ^ (ar & 7);
        af[m] = *(const bf16x8*)&As[ar * 64 + cp * 8];
      }
#pragma unroll
      for (int n = 0; n < 7; ++n) {
        const int br = wc * 112 + n * 16 + fr;
        const int cp = (s * 4 + q) ^ (br & 7);
        bfr[n] = *(const bf16x8*)&Bs[br * 64 + cp * 8];
      }
#pragma unroll
      for (int m = 0; m < 2; ++m)
#pragma unroll
        for (int n = 0; n < 7; ++n)
          acc[m][n] = __builtin_amdgcn_mfma_f32_16x16x32_bf16(af[m], bfr[n], acc[m][n], 0, 0, 0);
    }
    __syncthreads();
  }

  if (set == 0) {
    float pA[2][4], pB[2][4];
#pragma unroll
    for (int m = 0; m < 2; ++m)
#pragma unroll
      for (int j = 0; j < 4; ++j) { pA[m][j] = 0.f; pB[m][j] = 0.f; }
#pragma unroll
    for (int n = 0; n < 7; ++n) {
      const int col = wc * 112 + n * 16 + fr;
      const float wd = wds[col];
      const float bv = bas[col];
#pragma unroll
      for (int m = 0; m < 2; ++m) {
#pragma unroll
        for (int j = 0; j < 4; ++j) {
          const int rl = wr * 32 + m * 16 + q * 4 + j;
          const float av = acc[m][n][j] + bv;
          pA[m][j] += wd * tanhf_fast(av + ahAs[rl]);
          pB[m][j] += wd * tanhf_fast(av + ahBs[rl]);
        }
      }
    }
#pragma unroll
    for (int m = 0; m < 2; ++m)
#pragma unroll
      for (int j = 0; j < 4; ++j) {
#pragma unroll
        for (int off = 1; off < 16; off <<= 1) {
          pA[m][j] += __shfl_xor(pA[m][j], off);
          pB[m][j] += __shfl_xor(pB[m][j], off);
        }
      }
    __syncthreads();
    if (wc == 0 && fr == 0) {
#pragma unroll
      for (int m = 0; m < 2; ++m)
#pragma unroll
        for (int j = 0; j < 4; ++j) {
          const int rl = wr * 32 + m * 16 + q * 4 + j;
          sbA[rl] = pA[m][j]; sbB[rl] = pB[m][j];
        }
    }
    __syncthreads();
    if (wc == 1 && fr == 0) {
#pragma unroll
      for (int m = 0; m < 2; ++m)
#pragma unroll
        for (int j = 0; j < 4; ++j) {
          const int rl = wr * 32 + m * 16 + q * 4 + j;
          sbA[rl] += pA[m][j]; sbB[rl] += pB[m][j];
        }
    }
    __syncthreads();
    if (tid < 128) {
      s0[row0 + tid] = sbA[tid];
      s1[row0 + tid] = sbB[tid];
    }
  } else {
#pragma unroll
    for (int n = 0; n < 7; ++n) {
      const int col = wc * 112 + n * 16 + fr;
      if (col >= An) continue;
      const float bv = bas[col];
#pragma unroll
      for (int m = 0; m < 2; ++m) {
#pragma unroll
        for (int j = 0; j < 4; ++j) {
          const long row = row0 + wr * 32 + m * 16 + q * 4 + j;
          av_out[row * An + col] = f2b(acc[m][n][j] + bv);
        }
      }
    }
  }
}

// ---- gate GEMM (unchanged from round 9)
__global__ __launch_bounds__(256)
void gemm_gate(const unsigned short* __restrict__ A, const unsigned short* __restrict__ Bm,
               const float* __restrict__ b1, const float* __restrict__ b2,
               const float* __restrict__ b3, float* __restrict__ C)
{
  __shared__ unsigned short As[128 * 32];
  __shared__ unsigned short Bs[128 * 32];
  const int tid = threadIdx.x;
  const int lane = tid & 63, w = tid >> 6;
  int bid = blockIdx.x;
  bid = (bid & 7) * (gridDim.x >> 3) + (bid >> 3);
  const int bx = bid & 63;
  const int by = bid >> 6;
  const long row0 = (long)by * 128;
  const long col0 = (long)bx * 128;
  const int wr = w >> 1, wc = w & 1;
  const int fr = lane & 15, q = lane >> 4;
  const int srow = lane >> 2, schk = lane & 3;

  f32x4 acc[4][4] = {};
  const unsigned short* A0 = A + row0 * Kcat + schk * 8;
  const unsigned short* B0 = Bm + col0 * Kcat + schk * 8;

  for (int kt = 0; kt < Kcat; kt += 32) {
#pragma unroll
    for (int i = 0; i < 2; ++i) {
      const int rr = (w * 2 + i) * 16 + srow;
      __builtin_amdgcn_global_load_lds(
          (const __attribute__((address_space(1))) unsigned int*)(A0 + (long)rr * Kcat + kt),
          (__attribute__((address_space(3))) unsigned int*)(As + (w * 2 + i) * 512),
          16, 0, 0);
      __builtin_amdgcn_global_load_lds(
          (const __attribute__((address_space(1))) unsigned int*)(B0 + (long)rr * Kcat + kt),
          (__attribute__((address_space(3))) unsigned int*)(Bs + (w * 2 + i) * 512),
          16, 0, 0);
    }
    __syncthreads();
    bf16x8 af[4], bfr[4];
#pragma unroll
    for (int m = 0; m < 4; ++m)
      af[m] = *(const bf16x8*)&As[(wr * 64 + m * 16 + fr) * 32 + q * 8];
#pragma unroll
    for (int n = 0; n < 4; ++n)
      bfr[n] = *(const bf16x8*)&Bs[(wc * 64 + n * 16 + fr) * 32 + q * 8];
#pragma unroll
    for (int m = 0; m < 4; ++m)
#pragma unroll
      for (int n = 0; n < 4; ++n)
        acc[m][n] = __builtin_amdgcn_mfma_f32_16x16x32_bf16(af[m], bfr[n], acc[m][n], 0, 0, 0);
    __syncthreads();
  }

  const int crow = wr * 64 + q * 4;
  const int ccol = wc * 64 + fr;
#pragma unroll
  for (int n = 0; n < 4; ++n) {
    const int col = (int)col0 + ccol + n * 16;
    const float bv = b1[col] + b2[col] + b3[col];
#pragma unroll
    for (int m = 0; m < 4; ++m) {
      const long rb = row0 + crow + m * 16;
#pragma unroll
      for (int j = 0; j < 4; ++j)
        C[(rb + j) * (long)Gn + col] = acc[m][n][j] + bv;
    }
  }
}

// ---- bf16 MFMA GEMM (small, ragged N) — used only for ahA/ahB
__global__ __launch_bounds__(256)
void gemm_bf(const unsigned short* __restrict__ A, const unsigned short* __restrict__ Bm,
             const float* __restrict__ bias, float* __restrict__ C,
             int N, int K, int ldc)
{
  constexpr int LDP = 56;
  __shared__ unsigned short As[128 * LDP];
  __shared__ unsigned short Bs[128 * LDP];
  const int tid = threadIdx.x;
  const long row0 = (long)blockIdx.y * 128;
  const int col0 = blockIdx.x * 128;
  const int wid = tid >> 6, lane = tid & 63;
  const int wr = wid >> 1, wc = wid & 1;
  const int fr = lane & 15, kg = (lane >> 4) * 8;

  f32x4 acc[4][4] = {};

  const int srow = tid >> 1;
  const int skh = tid & 1;
  const unsigned short* Ap = A + (row0 + srow) * (long)K + skh * 16;
  const int bcol = col0 + srow;
  const unsigned short* Bp = Bm + (long)(bcol < N ? bcol : N - 1) * K + skh * 16;

  ushort8_t a0 = *(const ushort8_t*)(Ap);
  ushort8_t a1 = *(const ushort8_t*)(Ap + 8);
  ushort8_t b0 = *(const ushort8_t*)(Bp);
  ushort8_t b1 = *(const ushort8_t*)(Bp + 8);

  const int sw = srow * LDP + skh * 16;
  for (int kt = 0; kt < K; kt += 32) {
    *(ushort8_t*)&As[sw] = a0;
    *(ushort8_t*)&As[sw + 8] = a1;
    *(ushort8_t*)&Bs[sw] = b0;
    *(ushort8_t*)&Bs[sw + 8] = b1;
    if (kt + 32 < K) {
      a0 = *(const ushort8_t*)(Ap + kt + 32);
      a1 = *(const ushort8_t*)(Ap + kt + 40);
      b0 = *(const ushort8_t*)(Bp + kt + 32);
      b1 = *(const ushort8_t*)(Bp + kt + 40);
    }
    __syncthreads();
    bf16x8 af[4], bfr[4];
#pragma unroll
    for (int m = 0; m < 4; ++m)
      af[m] = *(const bf16x8*)&As[(wr * 64 + m * 16 + fr) * LDP + kg];
#pragma unroll
    for (int n = 0; n < 4; ++n)
      bfr[n] = *(const bf16x8*)&Bs[(wc * 64 + n * 16 + fr) * LDP + kg];
#pragma unroll
    for (int m = 0; m < 4; ++m)
#pragma unroll
      for (int n = 0; n < 4; ++n)
        acc[m][n] = __builtin_amdgcn_mfma_f32_16x16x32_bf16(af[m], bfr[n], acc[m][n], 0, 0, 0);
    __syncthreads();
  }

  const int crow = wr * 64 + (lane >> 4) * 4;
  const int ccol = wc * 64 + fr;
#pragma unroll
  for (int n = 0; n < 4; ++n) {
    const int col = col0 + ccol + n * 16;
    if (col >= N) continue;
    const float bv = bias ? bias[col] : 0.f;
#pragma unroll
    for (int m = 0; m < 4; ++m) {
      const long rb = row0 + crow + m * 16;
#pragma unroll
      for (int j = 0; j < 4; ++j)
        C[(rb + j) * (long)ldc + col] = acc[m][n][j] + bv;
    }
  }
}

// ---- fused ah1 + score: wave-per-row; inline dot(nh_bf[b], wh2a1[s]) + bias
__global__ __launch_bounds__(256)
void score1f(const unsigned short* __restrict__ av,
             const unsigned short* __restrict__ nh_bf,
             const unsigned short* __restrict__ wh1,
             const float* __restrict__ bh1,
             const float* __restrict__ Wd, float* __restrict__ s0)
{
  const int row = blockIdx.x * 4 + (threadIdx.x >> 6);
  const int lane = threadIdx.x & 63;
  const int b = row / An;
  const int s = row - b * An;

  float dot = 0.f;
  {
    ushort8_t nv = *(const ushort8_t*)(nh_bf + (long)b * 512 + lane * 8);
    ushort8_t wv = *(const ushort8_t*)(wh1 + (long)s * 512 + lane * 8);
#pragma unroll
    for (int j = 0; j < 8; ++j) dot = fmaf(b2f(nv[j]), b2f(wv[j]), dot);
  }
#pragma unroll
  for (int o = 32; o; o >>= 1) dot += __shfl_xor(dot, o);
  const float A0 = dot + bh1[s];

  float v0 = 0.f;
  if (lane < 49) {
    ushort4 u = *(const ushort4*)(av + (long)row * An + lane * 4);
    float4 w = *(const float4*)(Wd + lane * 4);
    v0 = w.x * tanhf_fast(b2f(u.x) + A0) + w.y * tanhf_fast(b2f(u.y) + A0)
       + w.z * tanhf_fast(b2f(u.z) + A0) + w.w * tanhf_fast(b2f(u.w) + A0);
  }
#pragma unroll
  for (int o = 32; o; o >>= 1) v0 += __shfl_down(v0, o);
  if (lane == 0) s0[row] = v0;
}

// ---- dual first-attend: softmax + wsum -> X20/X21 att-sections (bf16)
__global__ __launch_bounds__(256)
void wsumA(const unsigned short* __restrict__ att,
           const float* __restrict__ scA, const float* __restrict__ scB,
           unsigned short* __restrict__ X20, unsigned short* __restrict__ X21)
{
  const int half = threadIdx.x >> 7;
  const int b = blockIdx.x * 2 + half;
  const int t = threadIdx.x & 127;
  const int wv = t >> 6;
  __shared__ float ws0[2][An], ws1[2][An];
  __shared__ float redm[2][2][2], redsum[2][2][2];

  const float r0a = scA[(long)b * An + t];
  const float r0b = (t + 128 < An) ? scA[(long)b * An + t + 128] : -3.0e38f;
  const float r1a = scB[(long)b * An + t];
  const float r1b = (t + 128 < An) ? scB[(long)b * An + t + 128] : -3.0e38f;
  float m0 = fmaxf(r0a, r0b), m1 = fmaxf(r1a, r1b);
#pragma unroll
  for (int o = 32; o; o >>= 1) {
    m0 = fmaxf(m0, __shfl_xor(m0, o));
    m1 = fmaxf(m1, __shfl_xor(m1, o));
  }
  if ((t & 63) == 0) { redm[0][half][wv] = m0; redm[1][half][wv] = m1; }
  __syncthreads();
  m0 = fmaxf(redm[0][half][0], redm[0][half][1]);
  m1 = fmaxf(redm[1][half][0], redm[1][half][1]);
  const float e0a = __expf(r0a - m0);
  const float e0b = (t + 128 < An) ? __expf(r0b - m0) : 0.f;
  const float e1a = __expf(r1a - m1);
  const float e1b = (t + 128 < An) ? __expf(r1b - m1) : 0.f;
  float sl0 = e0a + e0b, sl1 = e1a + e1b;
#pragma unroll
  for (int o = 32; o; o >>= 1) {
    sl0 += __shfl_xor(sl0, o);
    sl1 += __shfl_xor(sl1, o);
  }
  if ((t & 63) == 0) { redsum[0][half][wv] = sl0; redsum[1][half][wv] = sl1; }
  __syncthreads();
  const float inv0 = __builtin_amdgcn_rcpf(redsum[0][half][0] + redsum[0][half][1]);
  const float inv1 = __builtin_amdgcn_rcpf(redsum[1][half][0] + redsum[1][half][1]);
  ws0[half][t] = e0a * inv0;
  ws1[half][t] = e1a * inv1;
  if (t + 128 < An) {
    ws0[half][t + 128] = e0b * inv0;
    ws1[half][t + 128] = e1b * inv1;
  }
  __syncthreads();

  const unsigned short* ap = att + (long)b * An * Rn + t * 4;
  float a00 = 0, a01 = 0, a02 = 0, a03 = 0;
  float a10 = 0, a11 = 0, a12 = 0, a13 = 0;
  for (int s = 0; s < An; ++s) {
    ushort4 u = *(const ushort4*)(ap + (long)s * Rn);
    const float f0 = b2f(u.x), f1 = b2f(u.y), f2 = b2f(u.z), f3 = b2f(u.w);
    const float v0 = ws0[half][s];
    a00 = fmaf(f0, v0, a00); a01 = fmaf(f1, v0, a01);
    a02 = fmaf(f2, v0, a02); a03 = fmaf(f3, v0, a03);
    const float v1 = ws1[half][s];
    a10 = fmaf(f0, v1, a10); a11 = fmaf(f1, v1, a11);
    a12 = fmaf(f2, v1, a12); a13 = fmaf(f3, v1, a13);
  }
  const long base = (long)b * Kcat + 1024 + t * 4;
  ushort4 oA, oB;
  oA.x = f2b(a00); oA.y = f2b(a01); oA.z = f2b(a02); oA.w = f2b(a03);
  oB.x = f2b(a10); oB.y = f2b(a11); oB.z = f2b(a12); oB.w = f2b(a13);
  *(ushort4*)(X20 + base) = oA;
  *(ushort4*)(X21 + base) = oB;
}

// ---- single second-attend: softmax + wsum + nh add -> out f32 (+X21 x-section)
template<bool WX2>
__global__ __launch_bounds__(256)
void wsumB(const unsigned short* __restrict__ att,
           const float* __restrict__ sc, const float* __restrict__ nh,
           const float* __restrict__ xin,
           float* __restrict__ outp, unsigned short* __restrict__ X21)
{
  const int half = threadIdx.x >> 7;
  const int b = blockIdx.x * 2 + half;
  const int t = threadIdx.x & 127;
  const int wv = t >> 6;
  __shared__ float ws[2][An];
  __shared__ float redm[2][2], redsum[2][2];

  const float ra = sc[(long)b * An + t];
  const float rb = (t + 128 < An) ? sc[(long)b * An + t + 128] : -3.0e38f;
  float m0 = fmaxf(ra, rb);
#pragma unroll
  for (int o = 32; o; o >>= 1) m0 = fmaxf(m0, __shfl_xor(m0, o));
  if ((t & 63) == 0) redm[half][wv] = m0;
  __syncthreads();
  m0 = fmaxf(redm[half][0], redm[half][1]);
  const float ea = __expf(ra - m0);
  const float eb = (t + 128 < An) ? __expf(rb - m0) : 0.f;
  float sl = ea + eb;
#pragma unroll
  for (int o = 32; o; o >>= 1) sl += __shfl_xor(sl, o);
  if ((t & 63) == 0) redsum[half][wv] = sl;
  __syncthreads();
  const float inv = __builtin_amdgcn_rcpf(redsum[half][0] + redsum[half][1]);
  ws[half][t] = ea * inv;
  if (t + 128 < An) ws[half][t + 128] = eb * inv;
  __syncthreads();

  const unsigned short* ap = att + (long)b * An * Rn + t * 4;
  float a0 = 0, a1 = 0, a2 = 0, a3 = 0;
  for (int s = 0; s < An; ++s) {
    ushort4 u = *(const ushort4*)(ap + (long)s * Rn);
    const float w = ws[half][s];
    a0 = fmaf(b2f(u.x), w, a0); a1 = fmaf(b2f(u.y), w, a1);
    a2 = fmaf(b2f(u.z), w, a2); a3 = fmaf(b2f(u.w), w, a3);
  }
  const long base = (long)b * Rn + t * 4;
  float4 ad = *(const float4*)(nh + base);
  a0 += ad.x; a1 += ad.y; a2 += ad.z; a3 += ad.w;
  *(float4*)(outp + base) = make_float4(a0, a1, a2, a3);
  if (WX2) {
    float4 xv = *(const float4*)(xin + base);
    ushort4 o;
    o.x = f2b(a0 + xv.x); o.y = f2b(a1 + xv.y);
    o.z = f2b(a2 + xv.z); o.w = f2b(a3 + xv.w);
    *(ushort4*)(X21 + (long)b * Kcat + t * 4) = o;
  }
}

// ---- LSTM pointwise over P=4 parallels
__global__ __launch_bounds__(256)
void gates_pw(const float* __restrict__ sums, const float* __restrict__ prev_c,
              float* __restrict__ out_c, float* __restrict__ nh,
              unsigned short* __restrict__ nh_bf)
{
  const int i = blockIdx.x * 256 + threadIdx.x;
  const int b = i >> 9;
  const int r = i & 511;
  const float c = prev_c[i];
  float aC = 0.f, aH = 0.f;
#pragma unroll
  for (int p = 0; p < 4; ++p) {
    const float* sp = sums + (long)b * Gn + p * 2048 + r;
    const float ig = sigmf(sp[0]);
    const float fg = sigmf(sp[512]);
    const float og = sigmf(sp[1024]);
    const float it = tanhf_fast(sp[1536]);
    const float nc = fmaf(fg, c, ig * it);
    aC += nc;
    aH = fmaf(og, tanhf_fast(nc), aH);
  }
  out_c[i] = aC * 0.25f;
  const float hv = aH * 0.25f;
  nh[i] = hv;
  nh_bf[i] = f2b(hv);
}

} // namespace

extern "C" void kernel_launch(void* const* d_in, const int* in_sizes, int n_in,
                              void* d_out, int out_size, void* d_ws, size_t ws_size,
                              hipStream_t stream)
{
  const float* x      = (const float*)d_in[0];
  const float* att    = (const float*)d_in[1];
  const float* inputs = (const float*)d_in[2];
  const float* Wa2a   = (const float*)d_in[3];
  const float* ba2a   = (const float*)d_in[4];
  const float* Wh2a   = (const float*)d_in[5];
  const float* bh2a   = (const float*)d_in[6];
  const float* Wd2d   = (const float*)d_in[7];
  const float* Wa2a1  = (const float*)d_in[9];
  const float* ba2a1  = (const float*)d_in[10];
  const float* Wh2a1  = (const float*)d_in[11];
  const float* bh2a1  = (const float*)d_in[12];
  const float* Wd2d1  = (const float*)d_in[13];
  const float* Wi2h   = (const float*)d_in[15];
  const float* bi2h   = (const float*)d_in[16];
  const float* Wh2h   = (const float*)d_in[17];
  const float* bh2h   = (const float*)d_in[18];
  const float* Wa2h   = (const float*)d_in[19];
  const float* ba2h   = (const float*)d_in[20];
  (void)in_sizes; (void)n_in; (void)out_size; (void)ws_size;

  float* out = (float*)d_out;
  const float* prev_c0 = inputs + 0 * (long)Bn * Rn;
  const float* prev_c1 = inputs + 2 * (long)Bn * Rn;

  char* wsp = (char*)d_ws;
  size_t off = 0;
  auto alloc = [&](size_t bytes) -> void* {
    void* p = wsp + off;
    off += (bytes + 1023) & ~(size_t)1023;
    return p;
  };
  unsigned short* att_bf  = (unsigned short*)alloc(ROWS * Rn * 2);
  unsigned short* W2      = (unsigned short*)alloc((size_t)Gn * Kcat * 2);
  unsigned short* Wpad    = (unsigned short*)alloc((size_t)2 * NP * Rn * 2);
  unsigned short* whcat   = (unsigned short*)alloc((size_t)2 * An * Rn * 2);
  unsigned short* h01_bf  = (unsigned short*)alloc((size_t)2 * Bn * Rn * 2);
  unsigned short* nh_bf   = (unsigned short*)alloc((size_t)Bn * Rn * 2);
  unsigned short* X20     = (unsigned short*)alloc((size_t)Bn * Kcat * 2);
  unsigned short* X21     = (unsigned short*)alloc((size_t)Bn * Kcat * 2);
  unsigned short* av1_bf  = (unsigned short*)alloc(ROWS * An * 2);
  float* ahAB = (float*)alloc((size_t)2 * ROWS * 4);
  float* scA  = (float*)alloc(ROWS * 4);
  float* scB  = (float*)alloc(ROWS * 4);
  float* sc1  = (float*)alloc(ROWS * 4);
  float* nh   = (float*)alloc((size_t)Bn * Rn * 4);
  float* sums = (float*)alloc((size_t)Bn * Gn * 4);

  float* ahA = ahAB;
  float* ahB = ahAB + ROWS;
  unsigned short* wh2a_bf  = whcat;
  unsigned short* wh2a1_bf = whcat + (size_t)An * Rn;

  const dim3 blk(256);

  // ---- conversions / packs
  f2b_copy<<<dim3(50176), blk, 0, stream>>>(att, att_bf, ROWS * Rn);
  pack_all<<<dim3(7634), blk, 0, stream>>>(Wa2a, Wa2a1, Wh2a, Wh2a1, inputs, x,
                                           Wi2h, Wh2h, Wa2h,
                                           Wpad, whcat, h01_bf, X20, X21, W2);

  // ---- ah projections, both layers in one GEMM (M = 2048)
  gemm_bf<<<dim3(2, 16), blk, 0, stream>>>(h01_bf, wh2a_bf, bh2a, ahA, An, Rn, An);

  // ---- column-split projection (BK=64 + swizzle): set0 dual-score + set1 av1 cache
  av_cs<<<dim3(3136), dim3(512), 0, stream>>>(
      att_bf, Wpad, ba2a, ba2a1, Wd2d, ahA, ahB, scA, scB, av1_bf);

  // ---- dual first attends -> X20/X21 att sections (bf16)
  wsumA<<<dim3(Bn / 2), blk, 0, stream>>>(att_bf, scA, scB, X20, X21);

  // ---- layer 0 LSTM
  gemm_gate<<<dim3(512), blk, 0, stream>>>(X20, W2, bi2h, bh2h, ba2h, sums);
  gates_pw<<<dim3(Bn * Rn / 256), blk, 0, stream>>>(sums, prev_c0, out + 0, nh, nh_bf);

  // ---- layer 0 second attend -> top_h0 (out[1]) + X21 x-section
  score1f<<<dim3((int)(ROWS / 4)), blk, 0, stream>>>(av1_bf, nh_bf, wh2a1_bf, bh2a1, Wd2d1, sc1);
  wsumB<true><<<dim3(Bn / 2), blk, 0, stream>>>(att_bf, sc1, nh, x,
                                                out + (long)Bn * Rn, X21);

  // ---- layer 1 LSTM
  gemm_gate<<<dim3(512), blk, 0, stream>>>(X21, W2, bi2h, bh2h, ba2h, sums);
  gates_pw<<<dim3(Bn * Rn / 256), blk, 0, stream>>>(sums, prev_c1, out + 2 * (long)Bn * Rn, nh, nh_bf);

  // ---- layer 1 second attend -> top_h1 (out[3])
  score1f<<<dim3((int)(ROWS / 4)), blk, 0, stream>>>(av1_bf, nh_bf, wh2a1_bf, bh2a1, Wd2d1, sc1);
  wsumB<false><<<dim3(Bn / 2), blk, 0, stream>>>(att_bf, sc1, nh, (const float*)nullptr,
                                                 out + 3 * (long)Bn * Rn,
                                                 (unsigned short*)nullptr);
}

// Round 11
// 638.960 us; speedup vs baseline: 1.1423x; 1.1423x over previous
//
#include <hip/hip_runtime.h>
#include <math.h>

typedef __attribute__((ext_vector_type(8))) unsigned short ushort8_t;
typedef __attribute__((ext_vector_type(8))) short bf16x8;
typedef __attribute__((ext_vector_type(4))) float f32x4;

namespace {

constexpr int Bn = 1024;
constexpr int Rn = 512;
constexpr int An = 196;
constexpr int Gn = 8192;     // P*4R
constexpr int Kcat = 1536;   // 3*R
constexpr int NP = 224;      // padded att cols per set (14 frags)
constexpr long ROWS = (long)Bn * An;  // 200704

__device__ __forceinline__ float b2f(unsigned short u) {
  union { unsigned int i; float f; } v; v.i = ((unsigned int)u) << 16; return v.f;
}
__device__ __forceinline__ unsigned short f2b(float f) {
  union { float f; unsigned int i; } v; v.f = f;
  unsigned int r = v.i + 0x7fffu + ((v.i >> 16) & 1u);
  return (unsigned short)(r >> 16);
}
__device__ __forceinline__ float sigmf(float x) {
  return __builtin_amdgcn_rcpf(1.f + __expf(-x));
}
__device__ __forceinline__ float tanhf_fast(float x) {
  const float e = __expf(2.f * x);
  return 1.f - 2.f * __builtin_amdgcn_rcpf(e + 1.f);
}

// ---- f32 -> bf16 copy, 8 elems/thread
__global__ __launch_bounds__(256)
void f2b_copy(const float* __restrict__ src, unsigned short* __restrict__ dst, long n)
{
  long i = ((long)blockIdx.x * 256 + threadIdx.x) * 8;
  const long stride = (long)gridDim.x * 256 * 8;
  for (; i + 8 <= n; i += stride) {
    float4 a = *(const float4*)(src + i);
    float4 b = *(const float4*)(src + i + 4);
    ushort8_t o;
    o[0] = f2b(a.x); o[1] = f2b(a.y); o[2] = f2b(a.z); o[3] = f2b(a.w);
    o[4] = f2b(b.x); o[5] = f2b(b.y); o[6] = f2b(b.z); o[7] = f2b(b.w);
    *(ushort8_t*)(dst + i) = o;
  }
}

// ---- merged pack kernel (round-9 version, measured neutral)
__global__ __launch_bounds__(256)
void pack_all(const float* __restrict__ Wa0, const float* __restrict__ Wa1,
              const float* __restrict__ Wh0, const float* __restrict__ Wh1,
              const float* __restrict__ inputs, const float* __restrict__ x,
              const float* __restrict__ Wi, const float* __restrict__ Wh,
              const float* __restrict__ Wa,
              unsigned short* __restrict__ Wp, unsigned short* __restrict__ whcat,
              unsigned short* __restrict__ h01,
              unsigned short* __restrict__ X20, unsigned short* __restrict__ X21,
              unsigned short* __restrict__ W2)
{
  const int blk = blockIdx.x;
  if (blk < 112) {
    long i = ((long)blk * 256 + threadIdx.x) * 8;
    if (i >= 2L * NP * 512) return;
    const int set = (int)(i / (NP * 512));
    const int rem = (int)(i % (NP * 512));
    const int row = rem / 512, k = rem % 512;
    ushort8_t o;
    if (row < An) {
      const float* s = (set ? Wa1 : Wa0) + (long)row * 512 + k;
      float4 a = *(const float4*)s, b = *(const float4*)(s + 4);
      o[0] = f2b(a.x); o[1] = f2b(a.y); o[2] = f2b(a.z); o[3] = f2b(a.w);
      o[4] = f2b(b.x); o[5] = f2b(b.y); o[6] = f2b(b.z); o[7] = f2b(b.w);
    } else {
      o = ushort8_t{0,0,0,0,0,0,0,0};
    }
    *(ushort8_t*)(Wp + i) = o;
  } else if (blk < 210) {
    long i = ((long)(blk - 112) * 256 + threadIdx.x) * 8;
    if (i >= 2L * An * 512) return;
    const long half = (long)An * 512;
    const float* s = (i < half) ? Wh0 + i : Wh1 + (i - half);
    float4 v0 = *(const float4*)s, v1 = *(const float4*)(s + 4);
    ushort8_t o;
    o[0] = f2b(v0.x); o[1] = f2b(v0.y); o[2] = f2b(v0.z); o[3] = f2b(v0.w);
    o[4] = f2b(v1.x); o[5] = f2b(v1.y); o[6] = f2b(v1.z); o[7] = f2b(v1.w);
    *(ushort8_t*)(whcat + i) = o;
  } else if (blk < 722) {
    long i = ((long)(blk - 210) * 256 + threadIdx.x) * 8;
    if (i >= 2L * Bn * 512) return;
    const long half = (long)Bn * 512;
    const float* s = (i < half) ? inputs + half + i : inputs + 3 * half + (i - half);
    float4 v0 = *(const float4*)s, v1 = *(const float4*)(s + 4);
    ushort8_t o;
    o[0] = f2b(v0.x); o[1] = f2b(v0.y); o[2] = f2b(v0.z); o[3] = f2b(v0.w);
    o[4] = f2b(v1.x); o[5] = f2b(v1.y); o[6] = f2b(v1.z); o[7] = f2b(v1.w);
    *(ushort8_t*)(h01 + i) = o;
  } else if (blk < 1490) {
    long i = ((long)(blk - 722) * 256 + threadIdx.x) * 8;
    if (i >= 3L * Bn * 512) return;
    const int sec = (int)(i / ((long)Bn * 512));
    const long r = i % ((long)Bn * 512);
    const int b = (int)(r >> 9);
    const int k = (int)(r & 511);
    const float* src = (sec == 0 ? x
                     : sec == 1 ? inputs + (long)Bn * Rn
                     : inputs + 3L * Bn * Rn) + r;
    unsigned short* dst = (sec == 2 ? X21 : X20) + (long)b * Kcat + (sec ? 512 : 0) + k;
    float4 v0 = *(const float4*)src, v1 = *(const float4*)(src + 4);
    ushort8_t o;
    o[0] = f2b(v0.x); o[1] = f2b(v0.y); o[2] = f2b(v0.z); o[3] = f2b(v0.w);
    o[4] = f2b(v1.x); o[5] = f2b(v1.y); o[6] = f2b(v1.z); o[7] = f2b(v1.w);
    *(ushort8_t*)dst = o;
  } else {
    long i = ((long)(blk - 1490) * 256 + threadIdx.x) * 8;
    if (i >= (long)Gn * Kcat) return;
    const int g = (int)(i / Kcat);
    const int k = (int)(i % Kcat);
    const float* src = (k < 512) ? Wi + (long)g * 512 + k
                     : (k < 1024) ? Wh + (long)g * 512 + (k - 512)
                     : Wa + (long)g * 512 + (k - 1024);
    float4 a = *(const float4*)src;
    float4 b = *(const float4*)(src + 4);
    ushort8_t o;
    o[0] = f2b(a.x); o[1] = f2b(a.y); o[2] = f2b(a.z); o[3] = f2b(a.w);
    o[4] = f2b(b.x); o[5] = f2b(b.y); o[6] = f2b(b.z); o[7] = f2b(b.w);
    *(ushort8_t*)(W2 + i) = o;
  }
}

// ---- column-split att-projection (round-8 measured-best version: BK=32)
__global__ __launch_bounds__(512, 4)
void av_cs(const unsigned short* __restrict__ A,
           const unsigned short* __restrict__ Wpad,
           const float* __restrict__ b0vec, const float* __restrict__ b1vec,
           const float* __restrict__ Wd,
           const float* __restrict__ ah0, const float* __restrict__ ah1,
           float* __restrict__ s0, float* __restrict__ s1,
           unsigned short* __restrict__ av_out)
{
  __shared__ unsigned short As[128 * 32];
  __shared__ unsigned short Bs[224 * 32];
  __shared__ float wds[NP], bas[NP];
  __shared__ float ahAs[128], ahBs[128];
  __shared__ float sbA[128], sbB[128];

  const int tid = threadIdx.x;
  const int lane = tid & 63, w = tid >> 6;
  const int wr = w >> 1, wc = w & 1;
  const int fr = lane & 15, q = lane >> 4;
  const long row0 = (long)blockIdx.x * 128;
  const int set = blockIdx.y;

  if (set == 0) {
    if (tid < NP) {
      wds[tid] = (tid < An) ? Wd[tid] : 0.f;
      bas[tid] = (tid < An) ? b0vec[tid] : 0.f;
    }
    if (tid >= 256 && tid < 384) ahAs[tid - 256] = ah0[row0 + tid - 256];
    if (tid >= 384)              ahBs[tid - 384] = ah1[row0 + tid - 384];
  } else {
    if (tid < NP) bas[tid] = (tid < An) ? b1vec[tid] : 0.f;
  }

  const unsigned short* Ab = A + row0 * 512;
  const unsigned short* Bb = Wpad + (long)set * NP * 512;

  f32x4 acc[2][7] = {};

  const int grow = lane >> 2;
  const int gchk = (lane & 3) * 8;

  for (int kt = 0; kt < 512; kt += 32) {
    {
      const unsigned short* src = Ab + (long)(w * 16 + grow) * 512 + gchk + kt;
      __builtin_amdgcn_global_load_lds(
          (const __attribute__((address_space(1))) unsigned int*)src,
          (__attribute__((address_space(3))) unsigned int*)(As + w * 512), 16, 0, 0);
    }
    {
      const unsigned short* src = Bb + (long)(w * 16 + grow) * 512 + gchk + kt;
      __builtin_amdgcn_global_load_lds(
          (const __attribute__((address_space(1))) unsigned int*)src,
          (__attribute__((address_space(3))) unsigned int*)(Bs + w * 512), 16, 0, 0);
    }
    if (w < 6) {
      const unsigned short* src = Bb + (long)((w + 8) * 16 + grow) * 512 + gchk + kt;
      __builtin_amdgcn_global_load_lds(
          (const __attribute__((address_space(1))) unsigned int*)src,
          (__attribute__((address_space(3))) unsigned int*)(Bs + (w + 8) * 512), 16, 0, 0);
    }
    __syncthreads();
    bf16x8 af[2], bfr[7];
#pragma unroll
    for (int m = 0; m < 2; ++m)
      af[m] = *(const bf16x8*)&As[(wr * 32 + m * 16 + fr) * 32 + q * 8];
#pragma unroll
    for (int n = 0; n < 7; ++n)
      bfr[n] = *(const bf16x8*)&Bs[(wc * 112 + n * 16 + fr) * 32 + q * 8];
#pragma unroll
    for (int m = 0; m < 2; ++m)
#pragma unroll
      for (int n = 0; n < 7; ++n)
        acc[m][n] = __builtin_amdgcn_mfma_f32_16x16x32_bf16(af[m], bfr[n], acc[m][n], 0, 0, 0);
    __syncthreads();
  }

  if (set == 0) {
    float pA[2][4], pB[2][4];
#pragma unroll
    for (int m = 0; m < 2; ++m)
#pragma unroll
      for (int j = 0; j < 4; ++j) { pA[m][j] = 0.f; pB[m][j] = 0.f; }
#pragma unroll
    for (int n = 0; n < 7; ++n) {
      const int col = wc * 112 + n * 16 + fr;
      const float wd = wds[col];
      const float bv = bas[col];
#pragma unroll
      for (int m = 0; m < 2; ++m) {
#pragma unroll
        for (int j = 0; j < 4; ++j) {
          const int rl = wr * 32 + m * 16 + q * 4 + j;
          const float av = acc[m][n][j] + bv;
          pA[m][j] += wd * tanhf_fast(av + ahAs[rl]);
          pB[m][j] += wd * tanhf_fast(av + ahBs[rl]);
        }
      }
    }
#pragma unroll
    for (int m = 0; m < 2; ++m)
#pragma unroll
      for (int j = 0; j < 4; ++j) {
#pragma unroll
        for (int off = 1; off < 16; off <<= 1) {
          pA[m][j] += __shfl_xor(pA[m][j], off);
          pB[m][j] += __shfl_xor(pB[m][j], off);
        }
      }
    __syncthreads();
    if (wc == 0 && fr == 0) {
#pragma unroll
      for (int m = 0; m < 2; ++m)
#pragma unroll
        for (int j = 0; j < 4; ++j) {
          const int rl = wr * 32 + m * 16 + q * 4 + j;
          sbA[rl] = pA[m][j]; sbB[rl] = pB[m][j];
        }
    }
    __syncthreads();
    if (wc == 1 && fr == 0) {
#pragma unroll
      for (int m = 0; m < 2; ++m)
#pragma unroll
        for (int j = 0; j < 4; ++j) {
          const int rl = wr * 32 + m * 16 + q * 4 + j;
          sbA[rl] += pA[m][j]; sbB[rl] += pB[m][j];
        }
    }
    __syncthreads();
    if (tid < 128) {
      s0[row0 + tid] = sbA[tid];
      s1[row0 + tid] = sbB[tid];
    }
  } else {
#pragma unroll
    for (int n = 0; n < 7; ++n) {
      const int col = wc * 112 + n * 16 + fr;
      if (col >= An) continue;
      const float bv = bas[col];
#pragma unroll
      for (int m = 0; m < 2; ++m) {
#pragma unroll
        for (int j = 0; j < 4; ++j) {
          const long row = row0 + wr * 32 + m * 16 + q * 4 + j;
          av_out[row * An + col] = f2b(acc[m][n][j] + bv);
        }
      }
    }
  }
}

// ---- gate GEMM: C_bf16[1024,8192] = X2 * W2^T + (b1+b2+b3)
__global__ __launch_bounds__(256)
void gemm_gate(const unsigned short* __restrict__ A, const unsigned short* __restrict__ Bm,
               const float* __restrict__ b1, const float* __restrict__ b2,
               const float* __restrict__ b3, unsigned short* __restrict__ C)
{
  __shared__ unsigned short As[128 * 32];
  __shared__ unsigned short Bs[128 * 32];
  const int tid = threadIdx.x;
  const int lane = tid & 63, w = tid >> 6;
  int bid = blockIdx.x;
  bid = (bid & 7) * (gridDim.x >> 3) + (bid >> 3);
  const int bx = bid & 63;
  const int by = bid >> 6;
  const long row0 = (long)by * 128;
  const long col0 = (long)bx * 128;
  const int wr = w >> 1, wc = w & 1;
  const int fr = lane & 15, q = lane >> 4;
  const int srow = lane >> 2, schk = lane & 3;

  f32x4 acc[4][4] = {};
  const unsigned short* A0 = A + row0 * Kcat + schk * 8;
  const unsigned short* B0 = Bm + col0 * Kcat + schk * 8;

  for (int kt = 0; kt < Kcat; kt += 32) {
#pragma unroll
    for (int i = 0; i < 2; ++i) {
      const int rr = (w * 2 + i) * 16 + srow;
      __builtin_amdgcn_global_load_lds(
          (const __attribute__((address_space(1))) unsigned int*)(A0 + (long)rr * Kcat + kt),
          (__attribute__((address_space(3))) unsigned int*)(As + (w * 2 + i) * 512),
          16, 0, 0);
      __builtin_amdgcn_global_load_lds(
          (const __attribute__((address_space(1))) unsigned int*)(B0 + (long)rr * Kcat + kt),
          (__attribute__((address_space(3))) unsigned int*)(Bs + (w * 2 + i) * 512),
          16, 0, 0);
    }
    __syncthreads();
    bf16x8 af[4], bfr[4];
#pragma unroll
    for (int m = 0; m < 4; ++m)
      af[m] = *(const bf16x8*)&As[(wr * 64 + m * 16 + fr) * 32 + q * 8];
#pragma unroll
    for (int n = 0; n < 4; ++n)
      bfr[n] = *(const bf16x8*)&Bs[(wc * 64 + n * 16 + fr) * 32 + q * 8];
#pragma unroll
    for (int m = 0; m < 4; ++m)
#pragma unroll
      for (int n = 0; n < 4; ++n)
        acc[m][n] = __builtin_amdgcn_mfma_f32_16x16x32_bf16(af[m], bfr[n], acc[m][n], 0, 0, 0);
    __syncthreads();
  }

  const int crow = wr * 64 + q * 4;
  const int ccol = wc * 64 + fr;
#pragma unroll
  for (int n = 0; n < 4; ++n) {
    const int col = (int)col0 + ccol + n * 16;
    const float bv = b1[col] + b2[col] + b3[col];
#pragma unroll
    for (int m = 0; m < 4; ++m) {
      const long rb = row0 + crow + m * 16;
#pragma unroll
      for (int j = 0; j < 4; ++j)
        C[(rb + j) * (long)Gn + col] = f2b(acc[m][n][j] + bv);
    }
  }
}

// ---- bf16 MFMA GEMM (small, ragged N)
__global__ __launch_bounds__(256)
void gemm_bf(const unsigned short* __restrict__ A, const unsigned short* __restrict__ Bm,
             const float* __restrict__ bias, float* __restrict__ C,
             int N, int K, int ldc)
{
  constexpr int LDP = 56;
  __shared__ unsigned short As[128 * LDP];
  __shared__ unsigned short Bs[128 * LDP];
  const int tid = threadIdx.x;
  const long row0 = (long)blockIdx.y * 128;
  const int col0 = blockIdx.x * 128;
  const int wid = tid >> 6, lane = tid & 63;
  const int wr = wid >> 1, wc = wid & 1;
  const int fr = lane & 15, kg = (lane >> 4) * 8;

  f32x4 acc[4][4] = {};

  const int srow = tid >> 1;
  const int skh = tid & 1;
  const unsigned short* Ap = A + (row0 + srow) * (long)K + skh * 16;
  const int bcol = col0 + srow;
  const unsigned short* Bp = Bm + (long)(bcol < N ? bcol : N - 1) * K + skh * 16;

  ushort8_t a0 = *(const ushort8_t*)(Ap);
  ushort8_t a1 = *(const ushort8_t*)(Ap + 8);
  ushort8_t b0 = *(const ushort8_t*)(Bp);
  ushort8_t b1 = *(const ushort8_t*)(Bp + 8);

  const int sw = srow * LDP + skh * 16;
  for (int kt = 0; kt < K; kt += 32) {
    *(ushort8_t*)&As[sw] = a0;
    *(ushort8_t*)&As[sw + 8] = a1;
    *(ushort8_t*)&Bs[sw] = b0;
    *(ushort8_t*)&Bs[sw + 8] = b1;
    if (kt + 32 < K) {
      a0 = *(const ushort8_t*)(Ap + kt + 32);
      a1 = *(const ushort8_t*)(Ap + kt + 40);
      b0 = *(const ushort8_t*)(Bp + kt + 32);
      b1 = *(const ushort8_t*)(Bp + kt + 40);
    }
    __syncthreads();
    bf16x8 af[4], bfr[4];
#pragma unroll
    for (int m = 0; m < 4; ++m)
      af[m] = *(const bf16x8*)&As[(wr * 64 + m * 16 + fr) * LDP + kg];
#pragma unroll
    for (int n = 0; n < 4; ++n)
      bfr[n] = *(const bf16x8*)&Bs[(wc * 64 + n * 16 + fr) * LDP + kg];
#pragma unroll
    for (int m = 0; m < 4; ++m)
#pragma unroll
      for (int n = 0; n < 4; ++n)
        acc[m][n] = __builtin_amdgcn_mfma_f32_16x16x32_bf16(af[m], bfr[n], acc[m][n], 0, 0, 0);
    __syncthreads();
  }

  const int crow = wr * 64 + (lane >> 4) * 4;
  const int ccol = wc * 64 + fr;
#pragma unroll
  for (int n = 0; n < 4; ++n) {
    const int col = col0 + ccol + n * 16;
    if (col >= N) continue;
    const float bv = bias ? bias[col] : 0.f;
#pragma unroll
    for (int m = 0; m < 4; ++m) {
      const long rb = row0 + crow + m * 16;
#pragma unroll
      for (int j = 0; j < 4; ++j)
        C[(rb + j) * (long)ldc + col] = acc[m][n][j] + bv;
    }
  }
}

// ---- score over cached bf16 av: one wave per row, ushort4 loads (49 lanes)
__global__ __launch_bounds__(256)
void score1(const unsigned short* __restrict__ av, const float* __restrict__ ah,
            const float* __restrict__ Wd, float* __restrict__ s0)
{
  const int row = blockIdx.x * 4 + (threadIdx.x >> 6);
  const int lane = threadIdx.x & 63;
  const float A0 = ah[row];
  float v0 = 0.f;
  if (lane < 49) {
    ushort4 u = *(const ushort4*)(av + (long)row * An + lane * 4);
    float4 w = *(const float4*)(Wd + lane * 4);
    v0 = w.x * tanhf_fast(b2f(u.x) + A0) + w.y * tanhf_fast(b2f(u.y) + A0)
       + w.z * tanhf_fast(b2f(u.z) + A0) + w.w * tanhf_fast(b2f(u.w) + A0);
  }
#pragma unroll
  for (int o = 32; o; o >>= 1) v0 += __shfl_down(v0, o);
  if (lane == 0) s0[row] = v0;
}

// ---- dual first-attend: softmax + wsum -> X20/X21 att-sections (bf16)
__global__ __launch_bounds__(256)
void wsumA(const unsigned short* __restrict__ att,
           const float* __restrict__ scA, const float* __restrict__ scB,
           unsigned short* __restrict__ X20, unsigned short* __restrict__ X21)
{
  const int half = threadIdx.x >> 7;
  const int b = blockIdx.x * 2 + half;
  const int t = threadIdx.x & 127;
  const int wv = t >> 6;
  __shared__ float ws0[2][An], ws1[2][An];
  __shared__ float redm[2][2][2], redsum[2][2][2];

  const float r0a = scA[(long)b * An + t];
  const float r0b = (t + 128 < An) ? scA[(long)b * An + t + 128] : -3.0e38f;
  const float r1a = scB[(long)b * An + t];
  const float r1b = (t + 128 < An) ? scB[(long)b * An + t + 128] : -3.0e38f;
  float m0 = fmaxf(r0a, r0b), m1 = fmaxf(r1a, r1b);
#pragma unroll
  for (int o = 32; o; o >>= 1) {
    m0 = fmaxf(m0, __shfl_xor(m0, o));
    m1 = fmaxf(m1, __shfl_xor(m1, o));
  }
  if ((t & 63) == 0) { redm[0][half][wv] = m0; redm[1][half][wv] = m1; }
  __syncthreads();
  m0 = fmaxf(redm[0][half][0], redm[0][half][1]);
  m1 = fmaxf(redm[1][half][0], redm[1][half][1]);
  const float e0a = __expf(r0a - m0);
  const float e0b = (t + 128 < An) ? __expf(r0b - m0) : 0.f;
  const float e1a = __expf(r1a - m1);
  const float e1b = (t + 128 < An) ? __expf(r1b - m1) : 0.f;
  float sl0 = e0a + e0b, sl1 = e1a + e1b;
#pragma unroll
  for (int o = 32; o; o >>= 1) {
    sl0 += __shfl_xor(sl0, o);
    sl1 += __shfl_xor(sl1, o);
  }
  if ((t & 63) == 0) { redsum[0][half][wv] = sl0; redsum[1][half][wv] = sl1; }
  __syncthreads();
  const float inv0 = __builtin_amdgcn_rcpf(redsum[0][half][0] + redsum[0][half][1]);
  const float inv1 = __builtin_amdgcn_rcpf(redsum[1][half][0] + redsum[1][half][1]);
  ws0[half][t] = e0a * inv0;
  ws1[half][t] = e1a * inv1;
  if (t + 128 < An) {
    ws0[half][t + 128] = e0b * inv0;
    ws1[half][t + 128] = e1b * inv1;
  }
  __syncthreads();

  const unsigned short* ap = att + (long)b * An * Rn + t * 4;
  float a00 = 0, a01 = 0, a02 = 0, a03 = 0;
  float a10 = 0, a11 = 0, a12 = 0, a13 = 0;
  for (int s = 0; s < An; ++s) {
    ushort4 u = *(const ushort4*)(ap + (long)s * Rn);
    const float f0 = b2f(u.x), f1 = b2f(u.y), f2 = b2f(u.z), f3 = b2f(u.w);
    const float v0 = ws0[half][s];
    a00 = fmaf(f0, v0, a00); a01 = fmaf(f1, v0, a01);
    a02 = fmaf(f2, v0, a02); a03 = fmaf(f3, v0, a03);
    const float v1 = ws1[half][s];
    a10 = fmaf(f0, v1, a10); a11 = fmaf(f1, v1, a11);
    a12 = fmaf(f2, v1, a12); a13 = fmaf(f3, v1, a13);
  }
  const long base = (long)b * Kcat + 1024 + t * 4;
  ushort4 oA, oB;
  oA.x = f2b(a00); oA.y = f2b(a01); oA.z = f2b(a02); oA.w = f2b(a03);
  oB.x = f2b(a10); oB.y = f2b(a11); oB.z = f2b(a12); oB.w = f2b(a13);
  *(ushort4*)(X20 + base) = oA;
  *(ushort4*)(X21 + base) = oB;
}

// ---- single second-attend: softmax + wsum + nh add -> out f32 (+X21 x-section)
template<bool WX2>
__global__ __launch_bounds__(256)
void wsumB(const unsigned short* __restrict__ att,
           const float* __restrict__ sc, const float* __restrict__ nh,
           const float* __restrict__ xin,
           float* __restrict__ outp, unsigned short* __restrict__ X21)
{
  const int half = threadIdx.x >> 7;
  const int b = blockIdx.x * 2 + half;
  const int t = threadIdx.x & 127;
  const int wv = t >> 6;
  __shared__ float ws[2][An];
  __shared__ float redm[2][2], redsum[2][2];

  const float ra = sc[(long)b * An + t];
  const float rb = (t + 128 < An) ? sc[(long)b * An + t + 128] : -3.0e38f;
  float m0 = fmaxf(ra, rb);
#pragma unroll
  for (int o = 32; o; o >>= 1) m0 = fmaxf(m0, __shfl_xor(m0, o));
  if ((t & 63) == 0) redm[half][wv] = m0;
  __syncthreads();
  m0 = fmaxf(redm[half][0], redm[half][1]);
  const float ea = __expf(ra - m0);
  const float eb = (t + 128 < An) ? __expf(rb - m0) : 0.f;
  float sl = ea + eb;
#pragma unroll
  for (int o = 32; o; o >>= 1) sl += __shfl_xor(sl, o);
  if ((t & 63) == 0) redsum[half][wv] = sl;
  __syncthreads();
  const float inv = __builtin_amdgcn_rcpf(redsum[half][0] + redsum[half][1]);
  ws[half][t] = ea * inv;
  if (t + 128 < An) ws[half][t + 128] = eb * inv;
  __syncthreads();

  const unsigned short* ap = att + (long)b * An * Rn + t * 4;
  float a0 = 0, a1 = 0, a2 = 0, a3 = 0;
  for (int s = 0; s < An; ++s) {
    ushort4 u = *(const ushort4*)(ap + (long)s * Rn);
    const float w = ws[half][s];
    a0 = fmaf(b2f(u.x), w, a0); a1 = fmaf(b2f(u.y), w, a1);
    a2 = fmaf(b2f(u.z), w, a2); a3 = fmaf(b2f(u.w), w, a3);
  }
  const long base = (long)b * Rn + t * 4;
  float4 ad = *(const float4*)(nh + base);
  a0 += ad.x; a1 += ad.y; a2 += ad.z; a3 += ad.w;
  *(float4*)(outp + base) = make_float4(a0, a1, a2, a3);
  if (WX2) {
    float4 xv = *(const float4*)(xin + base);
    ushort4 o;
    o.x = f2b(a0 + xv.x); o.y = f2b(a1 + xv.y);
    o.z = f2b(a2 + xv.z); o.w = f2b(a3 + xv.w);
    *(ushort4*)(X21 + (long)b * Kcat + t * 4) = o;
  }
}

// ---- LSTM pointwise over P=4 parallels (bf16 sums input)
__global__ __launch_bounds__(256)
void gates_pw(const unsigned short* __restrict__ sums, const float* __restrict__ prev_c,
              float* __restrict__ out_c, float* __restrict__ nh,
              unsigned short* __restrict__ nh_bf)
{
  const int i = blockIdx.x * 256 + threadIdx.x;
  const int b = i >> 9;
  const int r = i & 511;
  const float c = prev_c[i];
  float aC = 0.f, aH = 0.f;
#pragma unroll
  for (int p = 0; p < 4; ++p) {
    const unsigned short* sp = sums + (long)b * Gn + p * 2048 + r;
    const float ig = sigmf(b2f(sp[0]));
    const float fg = sigmf(b2f(sp[512]));
    const float og = sigmf(b2f(sp[1024]));
    const float it = tanhf_fast(b2f(sp[1536]));
    const float nc = fmaf(fg, c, ig * it);
    aC += nc;
    aH = fmaf(og, tanhf_fast(nc), aH);
  }
  out_c[i] = aC * 0.25f;
  const float hv = aH * 0.25f;
  nh[i] = hv;
  nh_bf[i] = f2b(hv);
}

} // namespace

extern "C" void kernel_launch(void* const* d_in, const int* in_sizes, int n_in,
                              void* d_out, int out_size, void* d_ws, size_t ws_size,
                              hipStream_t stream)
{
  const float* x      = (const float*)d_in[0];
  const float* att    = (const float*)d_in[1];
  const float* inputs = (const float*)d_in[2];
  const float* Wa2a   = (const float*)d_in[3];
  const float* ba2a   = (const float*)d_in[4];
  const float* Wh2a   = (const float*)d_in[5];
  const float* bh2a   = (const float*)d_in[6];
  const float* Wd2d   = (const float*)d_in[7];
  const float* Wa2a1  = (const float*)d_in[9];
  const float* ba2a1  = (const float*)d_in[10];
  const float* Wh2a1  = (const float*)d_in[11];
  const float* bh2a1  = (const float*)d_in[12];
  const float* Wd2d1  = (const float*)d_in[13];
  const float* Wi2h   = (const float*)d_in[15];
  const float* bi2h   = (const float*)d_in[16];
  const float* Wh2h   = (const float*)d_in[17];
  const float* bh2h   = (const float*)d_in[18];
  const float* Wa2h   = (const float*)d_in[19];
  const float* ba2h   = (const float*)d_in[20];
  (void)in_sizes; (void)n_in; (void)out_size; (void)ws_size;

  float* out = (float*)d_out;
  const float* prev_c0 = inputs + 0 * (long)Bn * Rn;
  const float* prev_c1 = inputs + 2 * (long)Bn * Rn;

  char* wsp = (char*)d_ws;
  size_t off = 0;
  auto alloc = [&](size_t bytes) -> void* {
    void* p = wsp + off;
    off += (bytes + 1023) & ~(size_t)1023;
    return p;
  };
  unsigned short* att_bf  = (unsigned short*)alloc(ROWS * Rn * 2);
  unsigned short* W2      = (unsigned short*)alloc((size_t)Gn * Kcat * 2);
  unsigned short* Wpad    = (unsigned short*)alloc((size_t)2 * NP * Rn * 2);
  unsigned short* whcat   = (unsigned short*)alloc((size_t)2 * An * Rn * 2);
  unsigned short* h01_bf  = (unsigned short*)alloc((size_t)2 * Bn * Rn * 2);
  unsigned short* nh_bf   = (unsigned short*)alloc((size_t)Bn * Rn * 2);
  unsigned short* X20     = (unsigned short*)alloc((size_t)Bn * Kcat * 2);
  unsigned short* X21     = (unsigned short*)alloc((size_t)Bn * Kcat * 2);
  unsigned short* av1_bf  = (unsigned short*)alloc(ROWS * An * 2);
  unsigned short* sums    = (unsigned short*)alloc((size_t)Bn * Gn * 2);
  float* ahAB = (float*)alloc((size_t)2 * ROWS * 4);
  float* ah1  = (float*)alloc(ROWS * 4);
  float* scA  = (float*)alloc(ROWS * 4);
  float* scB  = (float*)alloc(ROWS * 4);
  float* sc1  = (float*)alloc(ROWS * 4);
  float* nh   = (float*)alloc((size_t)Bn * Rn * 4);

  float* ahA = ahAB;
  float* ahB = ahAB + ROWS;
  unsigned short* wh2a_bf  = whcat;
  unsigned short* wh2a1_bf = whcat + (size_t)An * Rn;

  const dim3 blk(256);

  // ---- conversions / packs
  f2b_copy<<<dim3(50176), blk, 0, stream>>>(att, att_bf, ROWS * Rn);
  pack_all<<<dim3(7634), blk, 0, stream>>>(Wa2a, Wa2a1, Wh2a, Wh2a1, inputs, x,
                                           Wi2h, Wh2h, Wa2h,
                                           Wpad, whcat, h01_bf, X20, X21, W2);

  // ---- ah projections, both layers in one GEMM (M = 2048)
  gemm_bf<<<dim3(2, 16), blk, 0, stream>>>(h01_bf, wh2a_bf, bh2a, ahA, An, Rn, An);

  // ---- column-split projection: set0 dual-score + set1 av1 cache
  av_cs<<<dim3((int)(ROWS / 128), 2), dim3(512), 0, stream>>>(
      att_bf, Wpad, ba2a, ba2a1, Wd2d, ahA, ahB, scA, scB, av1_bf);

  // ---- dual first attends -> X20/X21 att sections (bf16)
  wsumA<<<dim3(Bn / 2), blk, 0, stream>>>(att_bf, scA, scB, X20, X21);

  // ---- layer 0 LSTM
  gemm_gate<<<dim3(512), blk, 0, stream>>>(X20, W2, bi2h, bh2h, ba2h, sums);
  gates_pw<<<dim3(Bn * Rn / 256), blk, 0, stream>>>(sums, prev_c0, out + 0, nh, nh_bf);

  // ---- layer 0 second attend -> top_h0 (out[1]) + X21 x-section
  gemm_bf<<<dim3(2, Bn / 128), blk, 0, stream>>>(nh_bf, wh2a1_bf, bh2a1, ah1, An, Rn, An);
  score1<<<dim3((int)(ROWS / 4)), blk, 0, stream>>>(av1_bf, ah1, Wd2d1, sc1);
  wsumB<true><<<dim3(Bn / 2), blk, 0, stream>>>(att_bf, sc1, nh, x,
                                                out + (long)Bn * Rn, X21);

  // ---- layer 1 LSTM
  gemm_gate<<<dim3(512), blk, 0, stream>>>(X21, W2, bi2h, bh2h, ba2h, sums);
  gates_pw<<<dim3(Bn * Rn / 256), blk, 0, stream>>>(sums, prev_c1, out + 2 * (long)Bn * Rn, nh, nh_bf);

  // ---- layer 1 second attend -> top_h1 (out[3])
  gemm_bf<<<dim3(2, Bn / 128), blk, 0, stream>>>(nh_bf, wh2a1_bf, bh2a1, ah1, An, Rn, An);
  score1<<<dim3((int)(ROWS / 4)), blk, 0, stream>>>(av1_bf, ah1, Wd2d1, sc1);
  wsumB<false><<<dim3(Bn / 2), blk, 0, stream>>>(att_bf, sc1, nh, (const float*)nullptr,
                                                 out + 3 * (long)Bn * Rn,
                                                 (unsigned short*)nullptr);
}